// Round 19
// baseline (258.059 us; speedup 1.0000x reference)
//
#include <hip/hip_runtime.h>
#include <hip/hip_bf16.h>

// ---- int8 path: per-row dynamic quant of x, exact int8 W, i32 MFMA accum ----
// R19: B operand moved OUT of LDS into registers (direct global->reg loads,
// double-buffered one tile ahead). Rationale: R14-R18 established that the
// LDS window and MFMA window serialize (8 schedule variants null); the only
// working lever is SHRINKING a window. B-reads (384cy) + B-staging writes
// (~576cy combined with A) leave the LDS pipe; B comes from L2 (wq = 16.7MB,
// L3-resident; one load instr reads a contiguous 16x64B subtile).
#define BM 256
#define BN 256
#define BK 64          // 64 int8 per row per K-tile = one K=64 MFMA step
#define NSLOT 4        // ring of 4 A-slots, staged 3 ahead
#define LDS_BYTES (NSLOT * BM * BK)   // 65536 — A only (launch must match!)

typedef float  f32x4  __attribute__((ext_vector_type(4)));
typedef int    i32x4  __attribute__((ext_vector_type(4)));
typedef __bf16 bf16x8 __attribute__((ext_vector_type(8)));
typedef __bf16 bf16x4 __attribute__((ext_vector_type(4)));

__device__ __forceinline__ void gload_lds16(const void* g, void* l) {
    __builtin_amdgcn_global_load_lds(
        (const __attribute__((address_space(1))) void*)g,
        (__attribute__((address_space(3))) void*)l, 16, 0, 0);
}

// ------------- fused prepass: rowquant(x) + pack(W) in one launch ------------
__global__ __launch_bounds__(256)
void prep_fused(const float* __restrict__ x, const int* __restrict__ w,
                signed char* __restrict__ xq, unsigned* __restrict__ wq,
                float* __restrict__ xs, int K, int M, int n4w, int WB) {
    const int tid = threadIdx.x;
    const int b = blockIdx.x;

    if (b < M) {
        const float* xr = x + (size_t)b * K;
        const int n4 = K / 4;

        float mx = 0.f;
        for (int i = tid; i < n4; i += 256) {
            f32x4 v = ((const f32x4*)xr)[i];
            mx = fmaxf(mx, fmaxf(fmaxf(fabsf(v[0]), fabsf(v[1])),
                                 fmaxf(fabsf(v[2]), fabsf(v[3]))));
        }
#pragma unroll
        for (int off = 32; off; off >>= 1)
            mx = fmaxf(mx, __shfl_xor(mx, off));
        __shared__ float smx[4];
        if ((tid & 63) == 0) smx[tid >> 6] = mx;
        __syncthreads();
        mx = fmaxf(fmaxf(smx[0], smx[1]), fmaxf(smx[2], smx[3]));

        const float inv = mx > 0.f ? 127.f / mx : 0.f;
        if (tid == 0) xs[b] = mx / 127.f;

        unsigned* out = (unsigned*)(xq + (size_t)b * K);
        for (int i = tid; i < n4; i += 256) {   // re-read: row is L1-resident
            f32x4 v = ((const f32x4*)xr)[i];
            int q0 = __float2int_rn(v[0] * inv);
            int q1 = __float2int_rn(v[1] * inv);
            int q2 = __float2int_rn(v[2] * inv);
            int q3 = __float2int_rn(v[3] * inv);
            out[i] = (unsigned)(q0 & 255) | ((unsigned)(q1 & 255) << 8) |
                     ((unsigned)(q2 & 255) << 16) | ((unsigned)(q3 & 255) << 24);
        }
    } else {
        int i = (b - M) * 256 + tid;
        const int stride = WB * 256;
        for (; i < n4w; i += stride) {
            i32x4 v = ((const i32x4*)w)[i];
            wq[i] = (unsigned)(v[0] & 255) | ((unsigned)(v[1] & 255) << 8) |
                    ((unsigned)(v[2] & 255) << 16) | ((unsigned)(v[3] & 255) << 24);
        }
    }
}

// ------------- main GEMM: i8 16x16x64, A in LDS, B direct-to-registers -------
// LDS A-slot: row-major [256 rows][64 B], 16 KiB; quad swizzle q^((R>>1)&3)
// (proven 0-conflict). gload_lds dest linear; source carries inverse swizzle.
// B: per wave 4 frags/tile; pB[ni] lane pointer -> one global_load_dwordx4
// reads the full 16-row x 64B subtile (lanes l,l+16,l+32,l+48 = quads 0-3 of
// row l&15). Double-buffered in named even/odd reg sets (rule #20: static
// indices via 2-tile unrolled loop body).
// vmcnt ladder: per tile issue order PINNED by sched_barrier(0):
//   [B(t+1) x4] [SA(t+3) x2]  ->  at tile-t top, waiting vmcnt(2) completes
// everything through B(t) (incl. SA(t)); t==0: vmcnt(4) (prologue order
// SA0 | B0 | SA1 SA2); rem<2: vmcnt(0).
// WAR (A slots): SA(t+3) hits slot (t-1)&3, issued after barrier t; tile
// t-1's A-reads were consumed (compiler lgkm waits) before that barrier.

__global__ __launch_bounds__(512, 2)
void qlin_gemm_i8(const signed char* __restrict__ A,  // [M,K] int8 x-quant
                  const signed char* __restrict__ B,  // [N,K] int8 w
                  const float* __restrict__ xs,       // [M] x row scales
                  const float* __restrict__ scale,    // [N]
                  const float* __restrict__ bias,     // [N]
                  float* __restrict__ C, int M, int N, int K) {
    extern __shared__ signed char lds[];
    signed char* lA = lds;                       // [NSLOT][256*64]

    const int NTN = N / BN;
    const int nwg = gridDim.x;
    int bid = blockIdx.x;
    bid = (bid & 7) * (nwg >> 3) + (bid >> 3);   // XCD swizzle (nwg%8==0)
    const int tm = bid / NTN;
    const int tn = bid % NTN;

    const int tid  = threadIdx.x;
    const int lane = tid & 63;
    const int wid  = tid >> 6;     // 0..7
    const int wr   = wid >> 2;     // 0..1  (M half: 128 rows)
    const int wc   = wid & 3;      // 0..3  (N quarter: 64 cols)

    // A staging map: per j (0,1) lane covers row wid*32 + j*16 + (lane>>2),
    // physical quad lane&3; inverse swizzle on the global source quad.
    const int srow0 = wid * 32 + (lane >> 2);
    const int srow1 = srow0 + 16;
    const int gq0 = (lane & 3) ^ ((srow0 >> 1) & 3);
    const int gq1 = (lane & 3) ^ ((srow1 >> 1) & 3);
    const signed char* Ap0 = A + (size_t)(tm * BM + srow0) * K + gq0 * 16;
    const signed char* Ap1 = A + (size_t)(tm * BM + srow1) * K + gq1 * 16;

    const int NT = K / BK;

    auto STAGE_A = [&](int t) {
        signed char* d = lA + (t & (NSLOT - 1)) * (BM * BK) + wid * 2048;
        gload_lds16(Ap0 + t * BK, d);
        gload_lds16(Ap1 + t * BK, d + 1024);
    };

    const int fr = lane & 15;      // row within 16x16 fragment
    const int kq = lane >> 4;      // k-quad 0..3 (16 B each)

    auto AOFF = [&](int mi) {
        const int R = wr * 128 + mi * 16 + fr;
        return R * 64 + ((kq ^ ((R >> 1) & 3)) << 4);
    };

    // per-lane B pointers: frag ni covers rows wc*64 + ni*16 + fr
    const signed char* pB[4];
#pragma unroll
    for (int ni = 0; ni < 4; ++ni)
        pB[ni] = B + (size_t)(tn * BN + wc * 64 + ni * 16 + fr) * K + kq * 16;

    i32x4 acc[8][4];
#pragma unroll
    for (int mi = 0; mi < 8; ++mi)
#pragma unroll
        for (int ni = 0; ni < 4; ++ni) {
            acc[mi][ni][0] = 0; acc[mi][ni][1] = 0;
            acc[mi][ni][2] = 0; acc[mi][ni][3] = 0;
        }

    i32x4 bfE[4], bfO[4];   // even/odd tile B sets (named -> static indexing)

    // prologue (order pinned): SA0 | B0 | SA1 SA2  -> tile0 wait = vmcnt(4)
    STAGE_A(0);
    __builtin_amdgcn_sched_barrier(0);
#pragma unroll
    for (int ni = 0; ni < 4; ++ni)
        bfE[ni] = *(const i32x4*)(pB[ni]);
    __builtin_amdgcn_sched_barrier(0);
    if (NT > 1) STAGE_A(1);
    if (NT > 2) STAGE_A(2);

    auto TILE = [&](int t, i32x4* bcur, i32x4* bnxt) {
        const signed char* lAs = lA + (t & (NSLOT - 1)) * (BM * BK);
        const int rem = NT - 1 - t;

        if (t == 0)        asm volatile("s_waitcnt vmcnt(4)" ::: "memory");
        else if (rem >= 2) asm volatile("s_waitcnt vmcnt(2)" ::: "memory");
        else               asm volatile("s_waitcnt vmcnt(0)" ::: "memory");
        __builtin_amdgcn_s_barrier();

        // A frags from LDS (compiler inserts lgkm waits before MFMA)
        i32x4 af[8];
#pragma unroll
        for (int mi = 0; mi < 8; ++mi)
            af[mi] = *(const i32x4*)(lAs + AOFF(mi));

        // issue next-tile B loads, then A staging — ORDER PINNED
        if (t + 1 < NT) {
#pragma unroll
            for (int ni = 0; ni < 4; ++ni)
                bnxt[ni] = *(const i32x4*)(pB[ni] + (size_t)(t + 1) * BK);
        }
        __builtin_amdgcn_sched_barrier(0);
        if (t + 3 < NT) STAGE_A(t + 3);
        __builtin_amdgcn_sched_barrier(0);

        // ---- 32-MFMA cluster ----
#pragma unroll
        for (int mi = 0; mi < 8; ++mi)
#pragma unroll
            for (int ni = 0; ni < 4; ++ni)
                acc[mi][ni] = __builtin_amdgcn_mfma_i32_16x16x64_i8(
                    af[mi], bcur[ni], acc[mi][ni], 0, 0, 0);
    };

    for (int t = 0; t < NT; t += 2) {
        TILE(t, bfE, bfO);       // even tile: consume bfE, load bfO
        TILE(t + 1, bfO, bfE);   // odd tile: consume bfO, load bfE
    }

    // epilogue: 16x16 C/D layout: col = lane&15, row = (lane>>4)*4 + r
    const int rb = tm * BM + wr * 128 + (lane >> 4) * 4;
    const int cb = tn * BN + wc * 64 + fr;
#pragma unroll
    for (int mi = 0; mi < 8; ++mi) {
        const int m0 = rb + mi * 16;
        float sm[4];
#pragma unroll
        for (int r = 0; r < 4; ++r) sm[r] = xs[m0 + r];
#pragma unroll
        for (int ni = 0; ni < 4; ++ni) {
            const int n = cb + ni * 16;
            const float sc = scale[n];
            const float bs = bias[n];
#pragma unroll
            for (int r = 0; r < 4; ++r)
                C[(size_t)(m0 + r) * N + n] =
                    fmaf((float)acc[mi][ni][r], sm[r] * sc, bs);
        }
    }
}

// ---------------- fallback (reg-staged 128^2 bf16, any shape) ----------------
#define FBM 128
#define FBK 32

__device__ __forceinline__ int swz_elem(int row, int e) {
    return row * FBK + (e ^ (((row >> 1) & 3) << 3));
}

__global__ __launch_bounds__(256, 2)
void qlin_gemm_reg(const float* __restrict__ A, const int* __restrict__ W,
                   const float* __restrict__ scale, const float* __restrict__ bias,
                   float* __restrict__ C, int M, int N, int K) {
    __shared__ __bf16 lA[2][FBM * FBK];
    __shared__ __bf16 lB[2][FBM * FBK];
    const int NTN = N / FBM;
    const int nwg = gridDim.x;
    int bid = blockIdx.x;
    if ((nwg & 7) == 0) bid = (bid & 7) * (nwg >> 3) + (bid >> 3);
    const int tm = bid / NTN, tn = bid % NTN;
    const int tid = threadIdx.x, lane = tid & 63, wid = tid >> 6;
    const int wr = wid >> 1, wc = wid & 1;
    const int srow0 = tid >> 3, skq = tid & 7;
    const float* aptr = A + (size_t)(tm * FBM + srow0) * K + skq * 4;
    const int*   wptr = W + (size_t)(tn * FBM + srow0) * K + skq * 4;
    const size_t rstride = (size_t)32 * K;
    f32x4 sa[4]; i32x4 sw[4];
    auto LOAD = [&](int t) {
#pragma unroll
        for (int j = 0; j < 4; ++j) {
            sa[j] = *(const f32x4*)(aptr + (size_t)t * FBK + j * rstride);
            sw[j] = *(const i32x4*)(wptr + (size_t)t * FBK + j * rstride);
        }
    };
    auto STORE = [&](int buf) {
#pragma unroll
        for (int j = 0; j < 4; ++j) {
            const int idx = swz_elem(srow0 + j * 32, skq * 4);
            bf16x4 va = { (__bf16)sa[j][0], (__bf16)sa[j][1],
                          (__bf16)sa[j][2], (__bf16)sa[j][3] };
            bf16x4 vw = { (__bf16)(float)sw[j][0], (__bf16)(float)sw[j][1],
                          (__bf16)(float)sw[j][2], (__bf16)(float)sw[j][3] };
            *(bf16x4*)&lA[buf][idx] = va;
            *(bf16x4*)&lB[buf][idx] = vw;
        }
    };
    const f32x4 fzero = {0.f, 0.f, 0.f, 0.f};
    f32x4 acc[4][4];
#pragma unroll
    for (int i = 0; i < 4; ++i)
#pragma unroll
        for (int j = 0; j < 4; ++j) acc[i][j] = fzero;
    const int fr = lane & 15, fks = (lane >> 4) * 8;
    LOAD(0); STORE(0); __syncthreads();
    const int NT = K / FBK;
    for (int t = 0; t < NT; ++t) {
        const int buf = t & 1;
        if (t + 1 < NT) LOAD(t + 1);
        bf16x8 af[4], bfg[4];
#pragma unroll
        for (int mi = 0; mi < 4; ++mi)
            af[mi] = *(const bf16x8*)&lA[buf][swz_elem(wr * 64 + mi * 16 + fr, fks)];
#pragma unroll
        for (int ni = 0; ni < 4; ++ni)
            bfg[ni] = *(const bf16x8*)&lB[buf][swz_elem(wc * 64 + ni * 16 + fr, fks)];
#pragma unroll
        for (int mi = 0; mi < 4; ++mi)
#pragma unroll
            for (int ni = 0; ni < 4; ++ni)
                acc[mi][ni] = __builtin_amdgcn_mfma_f32_16x16x32_bf16(
                    af[mi], bfg[ni], acc[mi][ni], 0, 0, 0);
        if (t + 1 < NT) STORE(buf ^ 1);
        __syncthreads();
    }
    const int row0 = tm * FBM + wr * 64 + (lane >> 4) * 4;
    const int col0 = tn * FBM + wc * 64 + fr;
#pragma unroll
    for (int ni = 0; ni < 4; ++ni) {
        const int n = col0 + ni * 16;
        const float sc = scale[n], bs = bias[n];
#pragma unroll
        for (int mi = 0; mi < 4; ++mi) {
            const int m = row0 + mi * 16;
#pragma unroll
            for (int r = 0; r < 4; ++r)
                C[(size_t)(m + r) * N + n] = fmaf(acc[mi][ni][r], sc, bs);
        }
    }
}

extern "C" void kernel_launch(void* const* d_in, const int* in_sizes, int n_in,
                              void* d_out, int out_size, void* d_ws, size_t ws_size,
                              hipStream_t stream) {
    const float* x     = (const float*)d_in[0];
    const int*   w8    = (const int*)d_in[1];
    const float* scale = (const float*)d_in[2];
    const float* bias  = (const float*)d_in[3];
    float*       out   = (float*)d_out;

    const int DOUT = in_sizes[2];
    const int DIN  = in_sizes[1] / DOUT;
    const int M    = in_sizes[0] / DIN;

    const size_t need = (size_t)M * DIN + (size_t)DOUT * DIN + (size_t)M * 4;
    const int nwg = (M / BM) * (DOUT / BN);
    const int NT  = DIN / BK;
    const bool ok = (ws_size >= need) && (M % BM == 0) && (DOUT % BN == 0) &&
                    (DIN % BK == 0) && (nwg % 8 == 0) && (NT >= 4) &&
                    (NT % 2 == 0) && (DIN % 4 == 0);
    if (ok) {
        signed char* xq = (signed char*)d_ws;
        signed char* wq = xq + (size_t)M * DIN;
        float*       xs = (float*)(wq + (size_t)DOUT * DIN);
        const int WB = 2048;
        prep_fused<<<M + WB, 256, 0, stream>>>(x, w8, xq, (unsigned*)wq, xs,
                                               DIN, M, DOUT * DIN / 4, WB);
        hipFuncSetAttribute(reinterpret_cast<const void*>(qlin_gemm_i8),
                            hipFuncAttributeMaxDynamicSharedMemorySize, LDS_BYTES);
        qlin_gemm_i8<<<nwg, 512, LDS_BYTES, stream>>>(xq, wq, xs, scale, bias, out,
                                                      M, DOUT, DIN);
    } else {
        dim3 grid((M / FBM) * (DOUT / FBM));
        qlin_gemm_reg<<<grid, 256, 0, stream>>>(x, w8, scale, bias, out, M, DOUT, DIN);
    }
}

// Round 20
// 188.514 us; speedup vs baseline: 1.3689x; 1.3689x over previous
//
#include <hip/hip_runtime.h>
#include <hip/hip_bf16.h>

// ---- int8 path: per-row dynamic quant of x, exact int8 W, i32 MFMA accum ----
// R20 = exact revert to R18 (session best, 189.2 us total; GEMM ~141 us).
// R19's B-direct-from-global regressed (scattered 16-row loads, L2 pressure:
// GEMM 225 us, MfmaUtil 25%). Final structure:
//   - fused prepass (rowquant x + pack W), one launch, ~45 us
//   - 256^2 tile, 8 waves, i8 16x16x64 MFMA, NSLOT=4 counted-vmcnt ring,
//     free-run single barrier/tile, conflict-free swizzled LDS, no setprio
// Session evidence: 10 schedule/structure variants null/negative -> LDS and
// MFMA windows serialize on this structure; only window-shrinking helped
// (int8 switch, 16x16x64 shape, prepass fusion).
#define BM 256
#define BN 256
#define BK 64          // 64 int8 per row per K-tile = one K=64 MFMA step
#define NSLOT 4        // ring of 4 K-tile slots, staged 3 ahead
#define LDS_BYTES (2 * NSLOT * BM * BK)   // 131072 — MUST match launch config

typedef float  f32x4  __attribute__((ext_vector_type(4)));
typedef int    i32x4  __attribute__((ext_vector_type(4)));
typedef __bf16 bf16x8 __attribute__((ext_vector_type(8)));
typedef __bf16 bf16x4 __attribute__((ext_vector_type(4)));

__device__ __forceinline__ void gload_lds16(const void* g, void* l) {
    __builtin_amdgcn_global_load_lds(
        (const __attribute__((address_space(1))) void*)g,
        (__attribute__((address_space(3))) void*)l, 16, 0, 0);
}

// ------------- fused prepass: rowquant(x) + pack(W) in one launch ------------
// blocks [0, M):        per-row absmax quant of x -> xq, xs
// blocks [M, M+WB):     grid-stride pack of W int32 -> int8 (exact)
__global__ __launch_bounds__(256)
void prep_fused(const float* __restrict__ x, const int* __restrict__ w,
                signed char* __restrict__ xq, unsigned* __restrict__ wq,
                float* __restrict__ xs, int K, int M, int n4w, int WB) {
    const int tid = threadIdx.x;
    const int b = blockIdx.x;

    if (b < M) {
        const float* xr = x + (size_t)b * K;
        const int n4 = K / 4;

        float mx = 0.f;
        for (int i = tid; i < n4; i += 256) {
            f32x4 v = ((const f32x4*)xr)[i];
            mx = fmaxf(mx, fmaxf(fmaxf(fabsf(v[0]), fabsf(v[1])),
                                 fmaxf(fabsf(v[2]), fabsf(v[3]))));
        }
#pragma unroll
        for (int off = 32; off; off >>= 1)
            mx = fmaxf(mx, __shfl_xor(mx, off));
        __shared__ float smx[4];
        if ((tid & 63) == 0) smx[tid >> 6] = mx;
        __syncthreads();
        mx = fmaxf(fmaxf(smx[0], smx[1]), fmaxf(smx[2], smx[3]));

        const float inv = mx > 0.f ? 127.f / mx : 0.f;
        if (tid == 0) xs[b] = mx / 127.f;

        unsigned* out = (unsigned*)(xq + (size_t)b * K);
        for (int i = tid; i < n4; i += 256) {   // re-read: row is L1-resident
            f32x4 v = ((const f32x4*)xr)[i];
            int q0 = __float2int_rn(v[0] * inv);
            int q1 = __float2int_rn(v[1] * inv);
            int q2 = __float2int_rn(v[2] * inv);
            int q3 = __float2int_rn(v[3] * inv);
            out[i] = (unsigned)(q0 & 255) | ((unsigned)(q1 & 255) << 8) |
                     ((unsigned)(q2 & 255) << 16) | ((unsigned)(q3 & 255) << 24);
        }
    } else {
        int i = (b - M) * 256 + tid;
        const int stride = WB * 256;
        for (; i < n4w; i += stride) {
            i32x4 v = ((const i32x4*)w)[i];
            wq[i] = (unsigned)(v[0] & 255) | ((unsigned)(v[1] & 255) << 8) |
                    ((unsigned)(v[2] & 255) << 16) | ((unsigned)(v[3] & 255) << 24);
        }
    }
}

// ------------- main GEMM: i8 16x16x64 MFMA, free-run counted-vmcnt ring ------
// LDS K-tile slot (per operand): row-major [256 rows][64 B], 16 KiB.
//   phys 16B-quad of row R: q_phys = q ^ ((R>>1)&3)  (proven 0-conflict).
// gload_lds dest linear; GLOBAL source carries the inverse swizzle.
// Schedule: per tile one vmcnt-laddered barrier, all 12 ds_reads upfront,
// STAGE(t+3) in the read shadow, then a 32-MFMA cluster.
// vmcnt ladder (rem = NT-1-t): rem>=2 -> 8, rem==1 -> 4, else 0.
// WAR: STAGE(t+3) hits slot (t-1)&3, issued only after barrier t; tile
// t-1's reads were consumed (compiler lgkm waits) before that barrier.

__global__ __launch_bounds__(512, 2)
void qlin_gemm_i8(const signed char* __restrict__ A,  // [M,K] int8 x-quant
                  const signed char* __restrict__ B,  // [N,K] int8 w
                  const float* __restrict__ xs,       // [M] x row scales
                  const float* __restrict__ scale,    // [N]
                  const float* __restrict__ bias,     // [N]
                  float* __restrict__ C, int M, int N, int K) {
    extern __shared__ signed char lds[];
    signed char* lA = lds;                       // [NSLOT][256*64]
    signed char* lB = lds + NSLOT * (BM * BK);

    const int NTN = N / BN;
    const int nwg = gridDim.x;
    int bid = blockIdx.x;
    bid = (bid & 7) * (nwg >> 3) + (bid >> 3);   // XCD swizzle (nwg%8==0)
    const int tm = bid / NTN;
    const int tn = bid % NTN;

    const int tid  = threadIdx.x;
    const int lane = tid & 63;
    const int wid  = tid >> 6;     // 0..7
    const int wr   = wid >> 2;     // 0..1  (M half: 128 rows)
    const int wc   = wid & 3;      // 0..3  (N quarter: 64 cols)

    // staging map: per j (0,1) lane covers row wid*32 + j*16 + (lane>>2),
    // physical quad lane&3; inverse swizzle on the global source quad.
    const int srow0 = wid * 32 + (lane >> 2);
    const int srow1 = srow0 + 16;
    const int gq0 = (lane & 3) ^ ((srow0 >> 1) & 3);
    const int gq1 = (lane & 3) ^ ((srow1 >> 1) & 3);
    const signed char* Ap0 = A + (size_t)(tm * BM + srow0) * K + gq0 * 16;
    const signed char* Ap1 = A + (size_t)(tm * BM + srow1) * K + gq1 * 16;
    const signed char* Bp0 = B + (size_t)(tn * BN + srow0) * K + gq0 * 16;
    const signed char* Bp1 = B + (size_t)(tn * BN + srow1) * K + gq1 * 16;

    const int NT = K / BK;

    auto STAGE_A = [&](int t) {
        signed char* d = lA + (t & (NSLOT - 1)) * (BM * BK) + wid * 2048;
        gload_lds16(Ap0 + t * BK, d);
        gload_lds16(Ap1 + t * BK, d + 1024);
    };
    auto STAGE_B = [&](int t) {
        signed char* d = lB + (t & (NSLOT - 1)) * (BM * BK) + wid * 2048;
        gload_lds16(Bp0 + t * BK, d);
        gload_lds16(Bp1 + t * BK, d + 1024);
    };

    const int fr = lane & 15;      // row within 16x16 fragment
    const int kq = lane >> 4;      // k-quad 0..3 (16 B each)

    auto AOFF = [&](int mi) {
        const int R = wr * 128 + mi * 16 + fr;
        return R * 64 + ((kq ^ ((R >> 1) & 3)) << 4);
    };
    auto BOFF = [&](int ni) {
        const int R = wc * 64 + ni * 16 + fr;
        return R * 64 + ((kq ^ ((R >> 1) & 3)) << 4);
    };

    i32x4 acc[8][4];
#pragma unroll
    for (int mi = 0; mi < 8; ++mi)
#pragma unroll
        for (int ni = 0; ni < 4; ++ni) {
            acc[mi][ni][0] = 0; acc[mi][ni][1] = 0;
            acc[mi][ni][2] = 0; acc[mi][ni][3] = 0;
        }

    // prologue: stage tiles 0..2 (12 loads/thread total)
    for (int u = 0; u < 3 && u < NT; ++u) { STAGE_A(u); STAGE_B(u); }

    for (int t = 0; t < NT; ++t) {
        const signed char* lAs = lA + (t & (NSLOT - 1)) * (BM * BK);
        const signed char* lBs = lB + (t & (NSLOT - 1)) * (BM * BK);
        const int rem = NT - 1 - t;

        if (rem >= 2)      asm volatile("s_waitcnt vmcnt(8)" ::: "memory");
        else if (rem == 1) asm volatile("s_waitcnt vmcnt(4)" ::: "memory");
        else               asm volatile("s_waitcnt vmcnt(0)" ::: "memory");
        __builtin_amdgcn_s_barrier();   // only barrier this K-tile

        // ---- all 12 ds_reads upfront ----
        i32x4 af[8], bf[4];
#pragma unroll
        for (int mi = 0; mi < 8; ++mi)
            af[mi] = *(const i32x4*)(lAs + AOFF(mi));
#pragma unroll
        for (int ni = 0; ni < 4; ++ni)
            bf[ni] = *(const i32x4*)(lBs + BOFF(ni));

        // stage issue sits in the ds_read latency shadow
        if (t + 3 < NT) { STAGE_A(t + 3); STAGE_B(t + 3); }

        // ---- 32-MFMA cluster (independent accumulators) ----
#pragma unroll
        for (int mi = 0; mi < 8; ++mi)
#pragma unroll
            for (int ni = 0; ni < 4; ++ni)
                acc[mi][ni] = __builtin_amdgcn_mfma_i32_16x16x64_i8(
                    af[mi], bf[ni], acc[mi][ni], 0, 0, 0);
    }

    // epilogue: 16x16 C/D layout: col = lane&15, row = (lane>>4)*4 + r
    const int rb = tm * BM + wr * 128 + (lane >> 4) * 4;
    const int cb = tn * BN + wc * 64 + fr;
#pragma unroll
    for (int mi = 0; mi < 8; ++mi) {
        const int m0 = rb + mi * 16;
        float sm[4];
#pragma unroll
        for (int r = 0; r < 4; ++r) sm[r] = xs[m0 + r];
#pragma unroll
        for (int ni = 0; ni < 4; ++ni) {
            const int n = cb + ni * 16;
            const float sc = scale[n];
            const float bs = bias[n];
#pragma unroll
            for (int r = 0; r < 4; ++r)
                C[(size_t)(m0 + r) * N + n] =
                    fmaf((float)acc[mi][ni][r], sm[r] * sc, bs);
        }
    }
}

// ---------------- fallback (reg-staged 128^2 bf16, any shape) ----------------
#define FBM 128
#define FBK 32

__device__ __forceinline__ int swz_elem(int row, int e) {
    return row * FBK + (e ^ (((row >> 1) & 3) << 3));
}

__global__ __launch_bounds__(256, 2)
void qlin_gemm_reg(const float* __restrict__ A, const int* __restrict__ W,
                   const float* __restrict__ scale, const float* __restrict__ bias,
                   float* __restrict__ C, int M, int N, int K) {
    __shared__ __bf16 lA[2][FBM * FBK];
    __shared__ __bf16 lB[2][FBM * FBK];
    const int NTN = N / FBM;
    const int nwg = gridDim.x;
    int bid = blockIdx.x;
    if ((nwg & 7) == 0) bid = (bid & 7) * (nwg >> 3) + (bid >> 3);
    const int tm = bid / NTN, tn = bid % NTN;
    const int tid = threadIdx.x, lane = tid & 63, wid = tid >> 6;
    const int wr = wid >> 1, wc = wid & 1;
    const int srow0 = tid >> 3, skq = tid & 7;
    const float* aptr = A + (size_t)(tm * FBM + srow0) * K + skq * 4;
    const int*   wptr = W + (size_t)(tn * FBM + srow0) * K + skq * 4;
    const size_t rstride = (size_t)32 * K;
    f32x4 sa[4]; i32x4 sw[4];
    auto LOAD = [&](int t) {
#pragma unroll
        for (int j = 0; j < 4; ++j) {
            sa[j] = *(const f32x4*)(aptr + (size_t)t * FBK + j * rstride);
            sw[j] = *(const i32x4*)(wptr + (size_t)t * FBK + j * rstride);
        }
    };
    auto STORE = [&](int buf) {
#pragma unroll
        for (int j = 0; j < 4; ++j) {
            const int idx = swz_elem(srow0 + j * 32, skq * 4);
            bf16x4 va = { (__bf16)sa[j][0], (__bf16)sa[j][1],
                          (__bf16)sa[j][2], (__bf16)sa[j][3] };
            bf16x4 vw = { (__bf16)(float)sw[j][0], (__bf16)(float)sw[j][1],
                          (__bf16)(float)sw[j][2], (__bf16)(float)sw[j][3] };
            *(bf16x4*)&lA[buf][idx] = va;
            *(bf16x4*)&lB[buf][idx] = vw;
        }
    };
    const f32x4 fzero = {0.f, 0.f, 0.f, 0.f};
    f32x4 acc[4][4];
#pragma unroll
    for (int i = 0; i < 4; ++i)
#pragma unroll
        for (int j = 0; j < 4; ++j) acc[i][j] = fzero;
    const int fr = lane & 15, fks = (lane >> 4) * 8;
    LOAD(0); STORE(0); __syncthreads();
    const int NT = K / FBK;
    for (int t = 0; t < NT; ++t) {
        const int buf = t & 1;
        if (t + 1 < NT) LOAD(t + 1);
        bf16x8 af[4], bfg[4];
#pragma unroll
        for (int mi = 0; mi < 4; ++mi)
            af[mi] = *(const bf16x8*)&lA[buf][swz_elem(wr * 64 + mi * 16 + fr, fks)];
#pragma unroll
        for (int ni = 0; ni < 4; ++ni)
            bfg[ni] = *(const bf16x8*)&lB[buf][swz_elem(wc * 64 + ni * 16 + fr, fks)];
#pragma unroll
        for (int mi = 0; mi < 4; ++mi)
#pragma unroll
            for (int ni = 0; ni < 4; ++ni)
                acc[mi][ni] = __builtin_amdgcn_mfma_f32_16x16x32_bf16(
                    af[mi], bfg[ni], acc[mi][ni], 0, 0, 0);
        if (t + 1 < NT) STORE(buf ^ 1);
        __syncthreads();
    }
    const int row0 = tm * FBM + wr * 64 + (lane >> 4) * 4;
    const int col0 = tn * FBM + wc * 64 + fr;
#pragma unroll
    for (int ni = 0; ni < 4; ++ni) {
        const int n = col0 + ni * 16;
        const float sc = scale[n], bs = bias[n];
#pragma unroll
        for (int mi = 0; mi < 4; ++mi) {
            const int m = row0 + mi * 16;
#pragma unroll
            for (int r = 0; r < 4; ++r)
                C[(size_t)(m + r) * N + n] = fmaf(acc[mi][ni][r], sc, bs);
        }
    }
}

extern "C" void kernel_launch(void* const* d_in, const int* in_sizes, int n_in,
                              void* d_out, int out_size, void* d_ws, size_t ws_size,
                              hipStream_t stream) {
    const float* x     = (const float*)d_in[0];
    const int*   w8    = (const int*)d_in[1];
    const float* scale = (const float*)d_in[2];
    const float* bias  = (const float*)d_in[3];
    float*       out   = (float*)d_out;

    const int DOUT = in_sizes[2];
    const int DIN  = in_sizes[1] / DOUT;
    const int M    = in_sizes[0] / DIN;

    const size_t need = (size_t)M * DIN + (size_t)DOUT * DIN + (size_t)M * 4;
    const int nwg = (M / BM) * (DOUT / BN);
    const bool ok = (ws_size >= need) && (M % BM == 0) && (DOUT % BN == 0) &&
                    (DIN % BK == 0) && (nwg % 8 == 0) && (DIN / BK >= 4) &&
                    (DIN % 4 == 0);
    if (ok) {
        signed char* xq = (signed char*)d_ws;
        signed char* wq = xq + (size_t)M * DIN;
        float*       xs = (float*)(wq + (size_t)DOUT * DIN);
        const int WB = 2048;                       // W-pack blocks
        prep_fused<<<M + WB, 256, 0, stream>>>(x, w8, xq, (unsigned*)wq, xs,
                                               DIN, M, DOUT * DIN / 4, WB);
        hipFuncSetAttribute(reinterpret_cast<const void*>(qlin_gemm_i8),
                            hipFuncAttributeMaxDynamicSharedMemorySize, LDS_BYTES);
        qlin_gemm_i8<<<nwg, 512, LDS_BYTES, stream>>>(xq, wq, xs, scale, bias, out,
                                                      M, DOUT, DIN);
    } else {
        dim3 grid((M / FBM) * (DOUT / FBM));
        qlin_gemm_reg<<<grid, 256, 0, stream>>>(x, w8, scale, bias, out, M, DOUT, DIN);
    }
}